// Round 17
// baseline (111.432 us; speedup 1.0000x reference)
//
#include <hip/hip_runtime.h>
#include <hip/hip_bf16.h>
#include <stdint.h>

#define BB 2
#define NN 2048
#define DD 1024
#define HH 16
#define DHD 64
#define MTOT (BB*NN)      // 4096
#define QKVC (3*HH*DHD)   // 3072

typedef unsigned short u16;
typedef __attribute__((ext_vector_type(8))) short short8;
typedef __attribute__((ext_vector_type(4))) float f32x4;
typedef __attribute__((ext_vector_type(16))) float f32x16;

#define QSCALE (0.125f * 1.44269504088896f)   // 1/sqrt(64) * log2(e), folded into Q

#if __has_builtin(__builtin_amdgcn_exp2f)
#define EXP2(x) __builtin_amdgcn_exp2f(x)     // raw v_exp_f32: args bounded, no range fixup needed
#else
#define EXP2(x) exp2f(x)
#endif

static __device__ __forceinline__ u16 f2bf(float f) {
  union { float f; uint32_t u; } v; v.f = f;
  uint32_t r = (v.u + 0x7fffu + ((v.u >> 16) & 1u)) >> 16;
  return (u16)r;
}

static __device__ __forceinline__ uint32_t cvtpk_bf16(float lo, float hi) {
  uint32_t r;
  asm("v_cvt_pk_bf16_f32 %0, %1, %2" : "=v"(r) : "v"(lo), "v"(hi));
  return r;
}

static __device__ __forceinline__ float u2f(uint32_t u) {
  union { uint32_t u; float f; } v; v.u = u; return v.f;
}
static __device__ __forceinline__ uint32_t f2u(float f) {
  union { float f; uint32_t u; } v; v.f = f; return v.u;
}

static __device__ __forceinline__ void gload_lds16(const void* g, void* l) {
  __builtin_amdgcn_global_load_lds(
      (const __attribute__((address_space(1))) void*)g,
      (__attribute__((address_space(3))) void*)l, 16, 0, 0);
}

#define MFMA16(a, b, c) __builtin_amdgcn_mfma_f32_16x16x32_bf16((a), (b), (c), 0, 0, 0)
#define MFMA32(a, b, c) __builtin_amdgcn_mfma_f32_32x32x16_bf16((a), (b), (c), 0, 0, 0)

// ---------------- fused f32 -> bf16 convert (x, W_w, out_w in one launch) ----------------
__global__ void k_cvt_all(const float* __restrict__ x, const float* __restrict__ Ww,
                          const float* __restrict__ ow,
                          u16* __restrict__ xb, u16* __restrict__ wwb, u16* __restrict__ owb) {
  int i = blockIdx.x * blockDim.x + threadIdx.x;   // float4 index, 0..2097151
  const float* src; u16* dst; int off;
  if (i < 1048576)      { src = x;  dst = xb;  off = i; }
  else if (i < 1835008) { src = Ww; dst = wwb; off = i - 1048576; }
  else                  { src = ow; dst = owb; off = i - 1835008; }
  float4 v = ((const float4*)src)[off];
  ushort4 o;
  o.x = f2bf(v.x); o.y = f2bf(v.y); o.z = f2bf(v.z); o.w = f2bf(v.w);
  ((ushort4*)dst)[off] = o;
}

// ---------------- QKV GEMM (128x128, BK=32, dbuf 2-phase; EPI scatter) ----------------
template<int EPI, int BM, int BN>
__global__ __launch_bounds__(256, EPI ? 4 : 3) void k_gemm_bt(
    const u16* __restrict__ A,   // [M][K] bf16
    const u16* __restrict__ Bm,  // [NC][K] bf16
    const float* __restrict__ bias, // [NC] f32
    u16* __restrict__ Qo, u16* __restrict__ Ko, u16* __restrict__ Vt,
    float* __restrict__ Co,
    int M, int NC, int K)
{
  constexpr int WM = BM / 2, WN = BN / 2;
  constexpr int FM = WM / 16, FN = WN / 16;
  __shared__ alignas(16) u16 As[2][BM * 32];
  __shared__ alignas(16) u16 Bs[2][BN * 32];
  const int t = threadIdx.x;
  const int lane = t & 63;
  const int wid = t >> 6;
  const int wr = wid >> 1, wc = wid & 1;
  const int l16 = lane & 15, lg = lane >> 4;
  const int col0 = blockIdx.x * BN;
  const int row0 = blockIdx.y * BM;

  f32x4 acc[FM][FN];
#pragma unroll
  for (int i = 0; i < FM; ++i)
#pragma unroll
    for (int j = 0; j < FN; ++j) acc[i][j] = (f32x4){0.f, 0.f, 0.f, 0.f};

  // stage one BK=32 K-slab into buffer `buf`
  auto stage = [&](int buf, int tt) {
    const int kk = tt * 32;
#pragma unroll
    for (int i = 0; i < BM / 64; ++i) {
      int s = i * 256 + t;
      int r = s >> 2, c8 = (s & 3) * 8;
      gload_lds16(A + (size_t)(row0 + r) * K + kk + c8, ((char*)&As[buf][0]) + s * 16);
    }
#pragma unroll
    for (int i = 0; i < BN / 64; ++i) {
      int s = i * 256 + t;
      int r = s >> 2, c8 = (s & 3) * 8;
      gload_lds16(Bm + (size_t)(col0 + r) * K + kk + c8, ((char*)&Bs[buf][0]) + s * 16);
    }
  };

  auto compute = [&](int buf) {
    const u16* as = &As[buf][0];
    const u16* bs = &Bs[buf][0];
    short8 af[FM], bfr[FN];
#pragma unroll
    for (int i = 0; i < FM; ++i)
      af[i] = *(const short8*)&as[(wr * WM + i * 16 + l16) * 32 + lg * 8];
#pragma unroll
    for (int j = 0; j < FN; ++j)
      bfr[j] = *(const short8*)&bs[(wc * WN + j * 16 + l16) * 32 + lg * 8];
#pragma unroll
    for (int i = 0; i < FM; ++i)
#pragma unroll
      for (int j = 0; j < FN; ++j)
        acc[i][j] = MFMA16(af[i], bfr[j], acc[i][j]);
  };

  const int NT = K / 32;
  stage(0, 0);
  __syncthreads();                       // drains vmcnt(0): buf0 ready
  int cur = 0;
  for (int tt = 0; tt < NT; ++tt) {
    if (tt + 1 < NT) stage(cur ^ 1, tt + 1);   // async, overlaps compute
    compute(cur);
    __syncthreads();                     // drains vmcnt(0): next buf ready; LDS reads done
    cur ^= 1;
  }

  if (EPI == 1) {
#pragma unroll
    for (int j = 0; j < FN; ++j) {
      int col = col0 + wc * WN + j * 16 + l16;
      float bv = bias[col];
#pragma unroll
      for (int i = 0; i < FM; ++i) {
#pragma unroll
        for (int r = 0; r < 4; ++r) {
          int row = row0 + wr * WM + i * 16 + lg * 4 + r;
          Co[(size_t)row * NC + col] = acc[i][j][r] + bv;
        }
      }
    }
  } else {
#pragma unroll
    for (int j = 0; j < FN; ++j) {
      int col = col0 + wc * WN + j * 16 + l16;
      float bv = bias[col];
      int part = col >> 10, rem = col & 1023;
      int h = rem >> 6, dh = rem & 63;
#pragma unroll
      for (int i = 0; i < FM; ++i) {
        int rowb = row0 + wr * WM + i * 16 + lg * 4;   // multiple of 4
        int b = rowb >> 11;
        int nn = rowb & 2047;
        size_t bhN = (size_t)(b * HH + h) * NN;
        if (part == 0) {
#pragma unroll
          for (int r = 0; r < 4; ++r)
            Qo[(bhN + nn + r) * DHD + dh] = f2bf((acc[i][j][r] + bv) * QSCALE);
        } else if (part == 1) {
#pragma unroll
          for (int r = 0; r < 4; ++r) Ko[(bhN + nn + r) * DHD + dh] = f2bf(acc[i][j][r] + bv);
        } else {
          size_t base = ((size_t)(b * HH + h) * DHD + dh) * NN + nn;
          ushort4 pk;
          pk.x = f2bf(acc[i][j][0] + bv);
          pk.y = f2bf(acc[i][j][1] + bv);
          pk.z = f2bf(acc[i][j][2] + bv);
          pk.w = f2bf(acc[i][j][3] + bv);
          *(ushort4*)&Vt[base] = pk;   // base%4==0 -> 8B aligned
        }
      }
    }
  }
}

// ---------------- proj GEMM: 64x64 tile, in-block K-split x2, BK=64, swizzled LDS --------
// 512 thr = 2 groups x 4 waves. Group g computes K range [g*512, g*512+512) into its own
// dbuf LDS pair: 8 barrier-locked K-steps per block instead of 16 (halved drain events,
// same staging bytes / MFMA count). Deterministic combine: group1 -> LDS, group0 adds +
// bias epilogue. LDS 64KB + 16KB overlay (80KB) -> 2 blocks/CU (same waves/CU as before).
__global__ __launch_bounds__(512, 4) void k_gemm64ks(
    const u16* __restrict__ A,   // [M][K] bf16
    const u16* __restrict__ Bm,  // [NC][K] bf16
    const float* __restrict__ bias, float* __restrict__ Co,
    int M, int NC, int K)
{
  __shared__ alignas(16) u16 As[2][2][64 * 64];   // [group][buf]
  __shared__ alignas(16) u16 Bs[2][2][64 * 64];
  __shared__ alignas(16) float carea[256 * 16];   // 16KB combine area
  const int t512 = threadIdx.x;
  const int g = t512 >> 8;            // wave-group 0/1
  const int t = t512 & 255;
  const int lane = t & 63, wid = t >> 6;
  const int wr = wid >> 1, wc = wid & 1;
  const int l16 = lane & 15, lg = lane >> 4;
  const int col0 = blockIdx.x * 64, row0 = blockIdx.y * 64;
  const int kbase = g * (K / 2);      // this group's K origin

  f32x4 acc[2][2];
#pragma unroll
  for (int i = 0; i < 2; ++i)
#pragma unroll
    for (int j = 0; j < 2; ++j) acc[i][j] = (f32x4){0.f, 0.f, 0.f, 0.f};

  auto stage = [&](int buf, int tt) {
    const int kk = kbase + tt * 64;
#pragma unroll
    for (int i = 0; i < 2; ++i) {
      int s = i * 256 + t;
      int r = s >> 3, so = ((s & 7) * 16) ^ ((r & 7) << 4);
      gload_lds16((const char*)(A + (size_t)(row0 + r) * K + kk) + so,
                  ((char*)&As[g][buf][0]) + s * 16);
    }
#pragma unroll
    for (int i = 0; i < 2; ++i) {
      int s = i * 256 + t;
      int r = s >> 3, so = ((s & 7) * 16) ^ ((r & 7) << 4);
      gload_lds16((const char*)(Bm + (size_t)(col0 + r) * K + kk) + so,
                  ((char*)&Bs[g][buf][0]) + s * 16);
    }
  };

  auto compute = [&](int buf) {
    const char* as = (const char*)&As[g][buf][0];
    const char* bs = (const char*)&Bs[g][buf][0];
#pragma unroll
    for (int kkh = 0; kkh < 2; ++kkh) {
      short8 af[2], bfr[2];
#pragma unroll
      for (int i = 0; i < 2; ++i) {
        int row = wr * 32 + i * 16 + l16;
        af[i] = *(const short8*)(as + row * 128 + ((kkh * 64 + lg * 16) ^ ((row & 7) << 4)));
      }
#pragma unroll
      for (int j = 0; j < 2; ++j) {
        int row = wc * 32 + j * 16 + l16;
        bfr[j] = *(const short8*)(bs + row * 128 + ((kkh * 64 + lg * 16) ^ ((row & 7) << 4)));
      }
#pragma unroll
      for (int i = 0; i < 2; ++i)
#pragma unroll
        for (int j = 0; j < 2; ++j)
          acc[i][j] = MFMA16(af[i], bfr[j], acc[i][j]);
    }
  };

  const int NT = K / 128;   // 8 steps per group (each group covers K/2 at BK=64)
  stage(0, 0);
  __syncthreads();
  int cur = 0;
  for (int tt = 0; tt < NT; ++tt) {
    if (tt + 1 < NT) stage(cur ^ 1, tt + 1);
    compute(cur);
    __syncthreads();
    cur ^= 1;
  }

  // ---- deterministic cross-group combine: group1 -> LDS, group0 adds ----
  if (g == 1) {
    float* dst = &carea[t * 16];
#pragma unroll
    for (int i = 0; i < 2; ++i)
#pragma unroll
      for (int j = 0; j < 2; ++j)
        *(f32x4*)&dst[(i * 2 + j) * 4] = acc[i][j];
  }
  __syncthreads();
  if (g == 1) return;
  {
    const float* src = &carea[t * 16];
#pragma unroll
    for (int i = 0; i < 2; ++i)
#pragma unroll
      for (int j = 0; j < 2; ++j) {
        f32x4 v = *(const f32x4*)&src[(i * 2 + j) * 4];
        acc[i][j][0] += v[0]; acc[i][j][1] += v[1];
        acc[i][j][2] += v[2]; acc[i][j][3] += v[3];
      }
  }

#pragma unroll
  for (int j = 0; j < 2; ++j) {
    int col = col0 + wc * 32 + j * 16 + l16;
    float bv = bias[col];
#pragma unroll
    for (int i = 0; i < 2; ++i)
#pragma unroll
      for (int r = 0; r < 4; ++r) {
        int row = row0 + wr * 32 + i * 16 + lg * 4 + r;
        Co[(size_t)row * NC + col] = acc[i][j][r] + bv;
      }
  }
}

// ---------------- flash attention (R13 known-good): dbuf staging, XCD-pinned heads -------
// grid 512 blocks (1D), 512 thr = 8 waves. Block decode pins all 16 qt-blocks of a
// given bh to ONE XCD (xcd = bid & 7). Group g = w>>2 handles kv half; wave wg owns
// q rows qt*128+wg*32. Q pre-scaled -> P = exp2(s) via raw v_exp_f32; cross-group
// combine = plain add. Double-buffered 2x16KB staging per group (64KB LDS).
__global__ __launch_bounds__(512, 4) void k_attn(
    const u16* __restrict__ Q, const u16* __restrict__ Kb,
    const u16* __restrict__ Vt, u16* __restrict__ AO)
{
  __shared__ alignas(16) char smem[65536];   // [g][2 x 16KB staging]; combine overlays
  const int t = threadIdx.x, lane = t & 63, w = t >> 6;   // w 0..7
  const int g = w >> 2, wg = w & 3;
  const int l32 = lane & 31, hi = lane >> 5;
  // XCD-pinning decode (performance-only permutation of (qt, bh))
  const int bid = blockIdx.x;
  const int xcd = bid & 7;
  const int idx = bid >> 3;          // 0..63
  const int bh = xcd * 4 + (idx >> 4);
  const int qt = idx & 15;
  const int b = bh >> 4, h = bh & 15;

  const u16* Qp  = Q + (size_t)bh * NN * DHD;
  const char* Kp = (const char*)(Kb + (size_t)bh * NN * DHD);
  const char* Vp = (const char*)(Vt + (size_t)bh * DHD * NN);

  const int q0 = qt * 128 + wg * 32;

  // Q B-fragments: lane holds Q[q0+l32][kk*16 + hi*8 .. +7]  (pre-scaled by QSCALE)
  short8 qf[4];
#pragma unroll
  for (int kk = 0; kk < 4; ++kk)
    qf[kk] = *(const short8*)&Qp[(size_t)(q0 + l32) * DHD + kk * 16 + hi * 8];

  f32x16 oacc[2];
  oacc[0] = (f32x16)(0.f);
  oacc[1] = (f32x16)(0.f);
  float lsv[4] = {0.f, 0.f, 0.f, 0.f};

  char* gbase = smem + g * 32768;
  const int kvbase = g * 1024;

  // Coalesced staging of one 64-kv tile (K 8KB + V^T 8KB), XOR-swizzled source
  // (rule #21: linear LDS dest + inverse-swizzled global source + swizzled read).
  const int srow = lane >> 3;             // 0..7
  const int scolb = (lane & 7) * 16;      // 0..112
  auto stage = [&](int buf, int kv) {
    char* base = gbase + buf * 16384;
#pragma unroll
    for (int i = 0; i < 2; ++i) {
      int r = wg * 16 + i * 8 + srow;     // kv-local row
      gload_lds16(Kp + (size_t)(kv + r) * 128 + (scolb ^ ((r & 7) << 4)),
                  base + wg * 2048 + i * 1024 + lane * 16);
    }
#pragma unroll
    for (int i = 0; i < 2; ++i) {
      int r = wg * 16 + i * 8 + srow;     // dh row
      gload_lds16(Vp + (size_t)r * (NN * 2) + (size_t)kv * 2 + (scolb ^ ((r & 7) << 4)),
                  base + 8192 + wg * 2048 + i * 1024 + lane * 16);
    }
  };

  // One 32-kv subtile: QK^T (4 MFMA) -> raw exp2 -> ls accum -> PV (4 MFMA)
  auto subtile = [&](const char* bufK, const char* bufV, int sub) {
    const int krow = sub * 32 + l32;
    const char* kro = bufK + krow * 128;
    const int ksw = (krow & 7) << 4;
    short8 kf[4];
#pragma unroll
    for (int kk = 0; kk < 4; ++kk)
      kf[kk] = *(const short8*)(kro + ((kk * 32 + hi * 16) ^ ksw));

    f32x16 s = (f32x16)(0.f);
#pragma unroll
    for (int kk = 0; kk < 4; ++kk) s = MFMA32(kf[kk], qf[kk], s);
    // lane holds s[r] = S[kv_local = (r&3)+8*(r>>2)+4*hi][q = l32]   (pre-scaled)

    float p[16];
#pragma unroll
    for (int r = 0; r < 16; ++r) p[r] = EXP2(s[r]);
#pragma unroll
    for (int r = 0; r < 16; ++r) lsv[r & 3] += p[r];

#pragma unroll
    for (int gs = 0; gs < 2; ++gs) {
      const int bix = gs * 8;
      uint32_t lo01 = cvtpk_bf16(p[bix + 0], p[bix + 1]);
      uint32_t lo23 = cvtpk_bf16(p[bix + 2], p[bix + 3]);
      uint32_t hi01 = cvtpk_bf16(p[bix + 4], p[bix + 5]);
      uint32_t hi23 = cvtpk_bf16(p[bix + 6], p[bix + 7]);
      auto ra = __builtin_amdgcn_permlane32_swap(lo01, hi01, false, false);
      auto rb = __builtin_amdgcn_permlane32_swap(lo23, hi23, false, false);
      union { uint32_t u[4]; short8 v; } pf;
      pf.u[0] = ra[0]; pf.u[1] = rb[0]; pf.u[2] = ra[1]; pf.u[3] = rb[1];
#pragma unroll
      for (int d = 0; d < 2; ++d) {
        const int vrow = d * 32 + l32;
        short8 vf = *(const short8*)(bufV + vrow * 128 +
                      ((sub * 64 + gs * 32 + hi * 16) ^ ((vrow & 7) << 4)));
        oacc[d] = MFMA32(vf, pf.v, oacc[d]);
      }
    }
  };

  // ---- 2-phase pipelined kv loop over this group's half (16 tiles of 64) ----
  const int NT = 16;
  stage(0, kvbase);
  asm volatile("s_waitcnt vmcnt(0)");
  __syncthreads();
  for (int t2 = 0; t2 < NT; ++t2) {
    int cur = t2 & 1;
    if (t2 + 1 < NT) stage(cur ^ 1, kvbase + (t2 + 1) * 64);
    const char* bK = gbase + cur * 16384;
    const char* bV = bK + 8192;
    subtile(bK, bV, 0);
    subtile(bK, bV, 1);
    asm volatile("s_waitcnt vmcnt(0)");
    __syncthreads();
  }

  // ---- cross-group combine: plain add of (O, ls) partials ----
  float ls = (lsv[0] + lsv[1]) + (lsv[2] + lsv[3]);
  {
    auto rr = __builtin_amdgcn_permlane32_swap(f2u(ls), f2u(ls), false, false);
    ls = u2f(rr[0]) + u2f(rr[1]);   // combine the two hi-half row subsets
  }
  float* lsarea = (float*)smem;             // [4][64], group-0 staging area (free)
  float* oarea  = (float*)(smem + 32768);   // [4][64][32], group-1 staging area (free)
  if (g == 1) {
    lsarea[wg * 64 + lane] = ls;
    float* dst = oarea + (size_t)(wg * 64 + lane) * 32;
#pragma unroll
    for (int d = 0; d < 2; ++d)
#pragma unroll
      for (int i = 0; i < 4; ++i)
        ((f32x4*)dst)[d * 4 + i] = (f32x4){oacc[d][i*4+0], oacc[d][i*4+1],
                                           oacc[d][i*4+2], oacc[d][i*4+3]};
  }
  __syncthreads();
  if (g == 1) return;

  float lst = ls + lsarea[wg * 64 + lane];
  {
    const float* src = oarea + (size_t)(wg * 64 + lane) * 32;
#pragma unroll
    for (int d = 0; d < 2; ++d)
#pragma unroll
      for (int i = 0; i < 4; ++i) {
        f32x4 v = ((const f32x4*)src)[d * 4 + i];
        oacc[d][i*4+0] += v[0]; oacc[d][i*4+1] += v[1];
        oacc[d][i*4+2] += v[2]; oacc[d][i*4+3] += v[3];
      }
  }

  // ---- epilogue: normalize, transpose via LDS, coalesced store ----
  u16* olw = (u16*)(smem + 1024) + (size_t)wg * 32 * 72;   // avoids lsarea
  float inv = 1.0f / lst;
#pragma unroll
  for (int d = 0; d < 2; ++d) {
#pragma unroll
    for (int i = 0; i < 8; ++i) {
      int r0 = 2 * i;
      int dh = d * 32 + (r0 & 3) + 8 * (r0 >> 2) + 4 * hi;
      uint32_t pk = cvtpk_bf16(oacc[d][r0] * inv, oacc[d][r0 + 1] * inv);
      *(uint32_t*)&olw[l32 * 72 + dh] = pk;
    }
  }
  __builtin_amdgcn_s_waitcnt(0);  // drain lgkm before same-wave readback
#pragma unroll
  for (int rr = 0; rr < 4; ++rr) {
    int row = rr * 8 + (lane >> 3);
    short8 v = *(const short8*)&olw[row * 72 + (lane & 7) * 8];
    int n = q0 + row;
    *(short8*)&AO[((size_t)b * NN + n) * DD + h * DHD + (lane & 7) * 8] = v;
  }
}

extern "C" void kernel_launch(void* const* d_in, const int* in_sizes, int n_in,
                              void* d_out, int out_size, void* d_ws, size_t ws_size,
                              hipStream_t stream) {
  const float* x  = (const float*)d_in[0];
  const float* Ww = (const float*)d_in[1];
  const float* Wb = (const float*)d_in[2];
  const float* ow = (const float*)d_in[3];
  const float* ob = (const float*)d_in[4];
  float* out = (float*)d_out;

  char* ws = (char*)d_ws;
  u16* xb  = (u16*)(ws);                       // 8 MB  x bf16 [4096][1024]
  u16* wwb = (u16*)(ws + ((size_t)8  << 20));  // 6 MB  W_w bf16 [3072][1024]
  u16* owb = (u16*)(ws + ((size_t)14 << 20));  // 2 MB  out_w bf16 [1024][1024]
  u16* Qb  = (u16*)(ws + ((size_t)16 << 20));  // 8 MB  Q [b,h,n,dh] (pre-scaled)
  u16* Kb  = (u16*)(ws + ((size_t)24 << 20));  // 8 MB  K [b,h,n,dh]
  u16* Vt  = (u16*)(ws + ((size_t)32 << 20));  // 8 MB  V^T [b,h,dh,n]
  u16* AO  = (u16*)(ws + ((size_t)40 << 20));  // 8 MB  attn out [b,n,h*dh]

  k_cvt_all<<<8192, 256, 0, stream>>>(x, Ww, ow, xb, wwb, owb);

  dim3 g1(QKVC / 128, MTOT / 128);  // (24, 32) -> 768 blocks, 3/CU
  k_gemm_bt<0, 128, 128><<<g1, 256, 0, stream>>>(xb, wwb, Wb, Qb, Kb, Vt, nullptr, MTOT, QKVC, DD);

  k_attn<<<512, 512, 0, stream>>>(Qb, Kb, Vt, AO);

  dim3 g3(DD / 64, MTOT / 64);      // (16, 64) -> 1024 blocks
  k_gemm64ks<<<g3, 512, 0, stream>>>(AO, owb, ob, out, MTOT, DD, DD);
}

// Round 18
// 108.454 us; speedup vs baseline: 1.0275x; 1.0275x over previous
//
#include <hip/hip_runtime.h>
#include <hip/hip_bf16.h>
#include <stdint.h>

#define BB 2
#define NN 2048
#define DD 1024
#define HH 16
#define DHD 64
#define MTOT (BB*NN)      // 4096
#define QKVC (3*HH*DHD)   // 3072

typedef unsigned short u16;
typedef __attribute__((ext_vector_type(8))) short short8;
typedef __attribute__((ext_vector_type(4))) float f32x4;
typedef __attribute__((ext_vector_type(16))) float f32x16;

#define QSCALE (0.125f * 1.44269504088896f)   // 1/sqrt(64) * log2(e), folded into Q

#if __has_builtin(__builtin_amdgcn_exp2f)
#define EXP2(x) __builtin_amdgcn_exp2f(x)     // raw v_exp_f32: args bounded, no range fixup needed
#else
#define EXP2(x) exp2f(x)
#endif

static __device__ __forceinline__ u16 f2bf(float f) {
  union { float f; uint32_t u; } v; v.f = f;
  uint32_t r = (v.u + 0x7fffu + ((v.u >> 16) & 1u)) >> 16;
  return (u16)r;
}

static __device__ __forceinline__ uint32_t cvtpk_bf16(float lo, float hi) {
  uint32_t r;
  asm("v_cvt_pk_bf16_f32 %0, %1, %2" : "=v"(r) : "v"(lo), "v"(hi));
  return r;
}

static __device__ __forceinline__ float u2f(uint32_t u) {
  union { uint32_t u; float f; } v; v.u = u; return v.f;
}
static __device__ __forceinline__ uint32_t f2u(float f) {
  union { float f; uint32_t u; } v; v.f = f; return v.u;
}

static __device__ __forceinline__ void gload_lds16(const void* g, void* l) {
  __builtin_amdgcn_global_load_lds(
      (const __attribute__((address_space(1))) void*)g,
      (__attribute__((address_space(3))) void*)l, 16, 0, 0);
}

#define MFMA16(a, b, c) __builtin_amdgcn_mfma_f32_16x16x32_bf16((a), (b), (c), 0, 0, 0)
#define MFMA32(a, b, c) __builtin_amdgcn_mfma_f32_32x32x16_bf16((a), (b), (c), 0, 0, 0)

// ---------------- fused f32 -> bf16 convert (x, W_w, out_w in one launch) ----------------
__global__ void k_cvt_all(const float* __restrict__ x, const float* __restrict__ Ww,
                          const float* __restrict__ ow,
                          u16* __restrict__ xb, u16* __restrict__ wwb, u16* __restrict__ owb) {
  int i = blockIdx.x * blockDim.x + threadIdx.x;   // float4 index, 0..2097151
  const float* src; u16* dst; int off;
  if (i < 1048576)      { src = x;  dst = xb;  off = i; }
  else if (i < 1835008) { src = Ww; dst = wwb; off = i - 1048576; }
  else                  { src = ow; dst = owb; off = i - 1835008; }
  float4 v = ((const float4*)src)[off];
  ushort4 o;
  o.x = f2bf(v.x); o.y = f2bf(v.y); o.z = f2bf(v.z); o.w = f2bf(v.w);
  ((ushort4*)dst)[off] = o;
}

// ---------------- QKV GEMM (128x128, BK=32, dbuf 2-phase; EPI scatter) ----------------
template<int EPI, int BM, int BN>
__global__ __launch_bounds__(256, EPI ? 4 : 3) void k_gemm_bt(
    const u16* __restrict__ A,   // [M][K] bf16
    const u16* __restrict__ Bm,  // [NC][K] bf16
    const float* __restrict__ bias, // [NC] f32
    u16* __restrict__ Qo, u16* __restrict__ Ko, u16* __restrict__ Vt,
    float* __restrict__ Co,
    int M, int NC, int K)
{
  constexpr int WM = BM / 2, WN = BN / 2;
  constexpr int FM = WM / 16, FN = WN / 16;
  __shared__ alignas(16) u16 As[2][BM * 32];
  __shared__ alignas(16) u16 Bs[2][BN * 32];
  const int t = threadIdx.x;
  const int lane = t & 63;
  const int wid = t >> 6;
  const int wr = wid >> 1, wc = wid & 1;
  const int l16 = lane & 15, lg = lane >> 4;
  const int col0 = blockIdx.x * BN;
  const int row0 = blockIdx.y * BM;

  f32x4 acc[FM][FN];
#pragma unroll
  for (int i = 0; i < FM; ++i)
#pragma unroll
    for (int j = 0; j < FN; ++j) acc[i][j] = (f32x4){0.f, 0.f, 0.f, 0.f};

  // stage one BK=32 K-slab into buffer `buf`
  auto stage = [&](int buf, int tt) {
    const int kk = tt * 32;
#pragma unroll
    for (int i = 0; i < BM / 64; ++i) {
      int s = i * 256 + t;
      int r = s >> 2, c8 = (s & 3) * 8;
      gload_lds16(A + (size_t)(row0 + r) * K + kk + c8, ((char*)&As[buf][0]) + s * 16);
    }
#pragma unroll
    for (int i = 0; i < BN / 64; ++i) {
      int s = i * 256 + t;
      int r = s >> 2, c8 = (s & 3) * 8;
      gload_lds16(Bm + (size_t)(col0 + r) * K + kk + c8, ((char*)&Bs[buf][0]) + s * 16);
    }
  };

  auto compute = [&](int buf) {
    const u16* as = &As[buf][0];
    const u16* bs = &Bs[buf][0];
    short8 af[FM], bfr[FN];
#pragma unroll
    for (int i = 0; i < FM; ++i)
      af[i] = *(const short8*)&as[(wr * WM + i * 16 + l16) * 32 + lg * 8];
#pragma unroll
    for (int j = 0; j < FN; ++j)
      bfr[j] = *(const short8*)&bs[(wc * WN + j * 16 + l16) * 32 + lg * 8];
#pragma unroll
    for (int i = 0; i < FM; ++i)
#pragma unroll
      for (int j = 0; j < FN; ++j)
        acc[i][j] = MFMA16(af[i], bfr[j], acc[i][j]);
  };

  const int NT = K / 32;
  stage(0, 0);
  __syncthreads();                       // drains vmcnt(0): buf0 ready
  int cur = 0;
  for (int tt = 0; tt < NT; ++tt) {
    if (tt + 1 < NT) stage(cur ^ 1, tt + 1);   // async, overlaps compute
    compute(cur);
    __syncthreads();                     // drains vmcnt(0): next buf ready; LDS reads done
    cur ^= 1;
  }

  if (EPI == 1) {
#pragma unroll
    for (int j = 0; j < FN; ++j) {
      int col = col0 + wc * WN + j * 16 + l16;
      float bv = bias[col];
#pragma unroll
      for (int i = 0; i < FM; ++i) {
#pragma unroll
        for (int r = 0; r < 4; ++r) {
          int row = row0 + wr * WM + i * 16 + lg * 4 + r;
          Co[(size_t)row * NC + col] = acc[i][j][r] + bv;
        }
      }
    }
  } else {
#pragma unroll
    for (int j = 0; j < FN; ++j) {
      int col = col0 + wc * WN + j * 16 + l16;
      float bv = bias[col];
      int part = col >> 10, rem = col & 1023;
      int h = rem >> 6, dh = rem & 63;
#pragma unroll
      for (int i = 0; i < FM; ++i) {
        int rowb = row0 + wr * WM + i * 16 + lg * 4;   // multiple of 4
        int b = rowb >> 11;
        int nn = rowb & 2047;
        size_t bhN = (size_t)(b * HH + h) * NN;
        if (part == 0) {
#pragma unroll
          for (int r = 0; r < 4; ++r)
            Qo[(bhN + nn + r) * DHD + dh] = f2bf((acc[i][j][r] + bv) * QSCALE);
        } else if (part == 1) {
#pragma unroll
          for (int r = 0; r < 4; ++r) Ko[(bhN + nn + r) * DHD + dh] = f2bf(acc[i][j][r] + bv);
        } else {
          size_t base = ((size_t)(b * HH + h) * DHD + dh) * NN + nn;
          ushort4 pk;
          pk.x = f2bf(acc[i][j][0] + bv);
          pk.y = f2bf(acc[i][j][1] + bv);
          pk.z = f2bf(acc[i][j][2] + bv);
          pk.w = f2bf(acc[i][j][3] + bv);
          *(ushort4*)&Vt[base] = pk;   // base%4==0 -> 8B aligned
        }
      }
    }
  }
}

// ---------------- proj GEMM: 64x64, BK=64, swizzled LDS, dbuf 2-phase (R16 best) ---------
__global__ __launch_bounds__(256, 4) void k_gemm64(
    const u16* __restrict__ A,   // [M][K] bf16
    const u16* __restrict__ Bm,  // [NC][K] bf16
    const float* __restrict__ bias, float* __restrict__ Co,
    int M, int NC, int K)
{
  __shared__ alignas(16) u16 As[2][64 * 64];
  __shared__ alignas(16) u16 Bs[2][64 * 64];
  const int t = threadIdx.x, lane = t & 63, wid = t >> 6;
  const int wr = wid >> 1, wc = wid & 1;
  const int l16 = lane & 15, lg = lane >> 4;
  const int col0 = blockIdx.x * 64, row0 = blockIdx.y * 64;

  f32x4 acc[2][2];
#pragma unroll
  for (int i = 0; i < 2; ++i)
#pragma unroll
    for (int j = 0; j < 2; ++j) acc[i][j] = (f32x4){0.f, 0.f, 0.f, 0.f};

  auto stage = [&](int buf, int tt) {
    const int kk = tt * 64;
#pragma unroll
    for (int i = 0; i < 2; ++i) {
      int s = i * 256 + t;
      int r = s >> 3, so = ((s & 7) * 16) ^ ((r & 7) << 4);
      gload_lds16((const char*)(A + (size_t)(row0 + r) * K + kk) + so,
                  ((char*)&As[buf][0]) + s * 16);
    }
#pragma unroll
    for (int i = 0; i < 2; ++i) {
      int s = i * 256 + t;
      int r = s >> 3, so = ((s & 7) * 16) ^ ((r & 7) << 4);
      gload_lds16((const char*)(Bm + (size_t)(col0 + r) * K + kk) + so,
                  ((char*)&Bs[buf][0]) + s * 16);
    }
  };

  auto compute = [&](int buf) {
    const char* as = (const char*)&As[buf][0];
    const char* bs = (const char*)&Bs[buf][0];
#pragma unroll
    for (int kkh = 0; kkh < 2; ++kkh) {
      short8 af[2], bfr[2];
#pragma unroll
      for (int i = 0; i < 2; ++i) {
        int row = wr * 32 + i * 16 + l16;
        af[i] = *(const short8*)(as + row * 128 + ((kkh * 64 + lg * 16) ^ ((row & 7) << 4)));
      }
#pragma unroll
      for (int j = 0; j < 2; ++j) {
        int row = wc * 32 + j * 16 + l16;
        bfr[j] = *(const short8*)(bs + row * 128 + ((kkh * 64 + lg * 16) ^ ((row & 7) << 4)));
      }
#pragma unroll
      for (int i = 0; i < 2; ++i)
#pragma unroll
        for (int j = 0; j < 2; ++j)
          acc[i][j] = MFMA16(af[i], bfr[j], acc[i][j]);
    }
  };

  const int NT = K / 64;   // 16
  stage(0, 0);
  __syncthreads();
  int cur = 0;
  for (int tt = 0; tt < NT; ++tt) {
    if (tt + 1 < NT) stage(cur ^ 1, tt + 1);
    compute(cur);
    __syncthreads();
    cur ^= 1;
  }

#pragma unroll
  for (int j = 0; j < 2; ++j) {
    int col = col0 + wc * 32 + j * 16 + l16;
    float bv = bias[col];
#pragma unroll
    for (int i = 0; i < 2; ++i)
#pragma unroll
      for (int r = 0; r < 4; ++r) {
        int row = row0 + wr * 32 + i * 16 + lg * 4 + r;
        Co[(size_t)row * NC + col] = acc[i][j][r] + bv;
      }
  }
}

// ---------------- flash attention (R13 known-good): dbuf staging, XCD-pinned heads -------
// grid 512 blocks (1D), 512 thr = 8 waves. Block decode pins all 16 qt-blocks of a
// given bh to ONE XCD (xcd = bid & 7). Group g = w>>2 handles kv half; wave wg owns
// q rows qt*128+wg*32. Q pre-scaled -> P = exp2(s) via raw v_exp_f32; cross-group
// combine = plain add. Double-buffered 2x16KB staging per group (64KB LDS).
__global__ __launch_bounds__(512, 4) void k_attn(
    const u16* __restrict__ Q, const u16* __restrict__ Kb,
    const u16* __restrict__ Vt, u16* __restrict__ AO)
{
  __shared__ alignas(16) char smem[65536];   // [g][2 x 16KB staging]; combine overlays
  const int t = threadIdx.x, lane = t & 63, w = t >> 6;   // w 0..7
  const int g = w >> 2, wg = w & 3;
  const int l32 = lane & 31, hi = lane >> 5;
  // XCD-pinning decode (performance-only permutation of (qt, bh))
  const int bid = blockIdx.x;
  const int xcd = bid & 7;
  const int idx = bid >> 3;          // 0..63
  const int bh = xcd * 4 + (idx >> 4);
  const int qt = idx & 15;
  const int b = bh >> 4, h = bh & 15;

  const u16* Qp  = Q + (size_t)bh * NN * DHD;
  const char* Kp = (const char*)(Kb + (size_t)bh * NN * DHD);
  const char* Vp = (const char*)(Vt + (size_t)bh * DHD * NN);

  const int q0 = qt * 128 + wg * 32;

  // Q B-fragments: lane holds Q[q0+l32][kk*16 + hi*8 .. +7]  (pre-scaled by QSCALE)
  short8 qf[4];
#pragma unroll
  for (int kk = 0; kk < 4; ++kk)
    qf[kk] = *(const short8*)&Qp[(size_t)(q0 + l32) * DHD + kk * 16 + hi * 8];

  f32x16 oacc[2];
  oacc[0] = (f32x16)(0.f);
  oacc[1] = (f32x16)(0.f);
  float lsv[4] = {0.f, 0.f, 0.f, 0.f};

  char* gbase = smem + g * 32768;
  const int kvbase = g * 1024;

  // Coalesced staging of one 64-kv tile (K 8KB + V^T 8KB), XOR-swizzled source
  // (rule #21: linear LDS dest + inverse-swizzled global source + swizzled read).
  const int srow = lane >> 3;             // 0..7
  const int scolb = (lane & 7) * 16;      // 0..112
  auto stage = [&](int buf, int kv) {
    char* base = gbase + buf * 16384;
#pragma unroll
    for (int i = 0; i < 2; ++i) {
      int r = wg * 16 + i * 8 + srow;     // kv-local row
      gload_lds16(Kp + (size_t)(kv + r) * 128 + (scolb ^ ((r & 7) << 4)),
                  base + wg * 2048 + i * 1024 + lane * 16);
    }
#pragma unroll
    for (int i = 0; i < 2; ++i) {
      int r = wg * 16 + i * 8 + srow;     // dh row
      gload_lds16(Vp + (size_t)r * (NN * 2) + (size_t)kv * 2 + (scolb ^ ((r & 7) << 4)),
                  base + 8192 + wg * 2048 + i * 1024 + lane * 16);
    }
  };

  // One 32-kv subtile: QK^T (4 MFMA) -> raw exp2 -> ls accum -> PV (4 MFMA)
  auto subtile = [&](const char* bufK, const char* bufV, int sub) {
    const int krow = sub * 32 + l32;
    const char* kro = bufK + krow * 128;
    const int ksw = (krow & 7) << 4;
    short8 kf[4];
#pragma unroll
    for (int kk = 0; kk < 4; ++kk)
      kf[kk] = *(const short8*)(kro + ((kk * 32 + hi * 16) ^ ksw));

    f32x16 s = (f32x16)(0.f);
#pragma unroll
    for (int kk = 0; kk < 4; ++kk) s = MFMA32(kf[kk], qf[kk], s);
    // lane holds s[r] = S[kv_local = (r&3)+8*(r>>2)+4*hi][q = l32]   (pre-scaled)

    float p[16];
#pragma unroll
    for (int r = 0; r < 16; ++r) p[r] = EXP2(s[r]);
#pragma unroll
    for (int r = 0; r < 16; ++r) lsv[r & 3] += p[r];

#pragma unroll
    for (int gs = 0; gs < 2; ++gs) {
      const int bix = gs * 8;
      uint32_t lo01 = cvtpk_bf16(p[bix + 0], p[bix + 1]);
      uint32_t lo23 = cvtpk_bf16(p[bix + 2], p[bix + 3]);
      uint32_t hi01 = cvtpk_bf16(p[bix + 4], p[bix + 5]);
      uint32_t hi23 = cvtpk_bf16(p[bix + 6], p[bix + 7]);
      auto ra = __builtin_amdgcn_permlane32_swap(lo01, hi01, false, false);
      auto rb = __builtin_amdgcn_permlane32_swap(lo23, hi23, false, false);
      union { uint32_t u[4]; short8 v; } pf;
      pf.u[0] = ra[0]; pf.u[1] = rb[0]; pf.u[2] = ra[1]; pf.u[3] = rb[1];
#pragma unroll
      for (int d = 0; d < 2; ++d) {
        const int vrow = d * 32 + l32;
        short8 vf = *(const short8*)(bufV + vrow * 128 +
                      ((sub * 64 + gs * 32 + hi * 16) ^ ((vrow & 7) << 4)));
        oacc[d] = MFMA32(vf, pf.v, oacc[d]);
      }
    }
  };

  // ---- 2-phase pipelined kv loop over this group's half (16 tiles of 64) ----
  const int NT = 16;
  stage(0, kvbase);
  asm volatile("s_waitcnt vmcnt(0)");
  __syncthreads();
  for (int t2 = 0; t2 < NT; ++t2) {
    int cur = t2 & 1;
    if (t2 + 1 < NT) stage(cur ^ 1, kvbase + (t2 + 1) * 64);
    const char* bK = gbase + cur * 16384;
    const char* bV = bK + 8192;
    subtile(bK, bV, 0);
    subtile(bK, bV, 1);
    asm volatile("s_waitcnt vmcnt(0)");
    __syncthreads();
  }

  // ---- cross-group combine: plain add of (O, ls) partials ----
  float ls = (lsv[0] + lsv[1]) + (lsv[2] + lsv[3]);
  {
    auto rr = __builtin_amdgcn_permlane32_swap(f2u(ls), f2u(ls), false, false);
    ls = u2f(rr[0]) + u2f(rr[1]);   // combine the two hi-half row subsets
  }
  float* lsarea = (float*)smem;             // [4][64], group-0 staging area (free)
  float* oarea  = (float*)(smem + 32768);   // [4][64][32], group-1 staging area (free)
  if (g == 1) {
    lsarea[wg * 64 + lane] = ls;
    float* dst = oarea + (size_t)(wg * 64 + lane) * 32;
#pragma unroll
    for (int d = 0; d < 2; ++d)
#pragma unroll
      for (int i = 0; i < 4; ++i)
        ((f32x4*)dst)[d * 4 + i] = (f32x4){oacc[d][i*4+0], oacc[d][i*4+1],
                                           oacc[d][i*4+2], oacc[d][i*4+3]};
  }
  __syncthreads();
  if (g == 1) return;

  float lst = ls + lsarea[wg * 64 + lane];
  {
    const float* src = oarea + (size_t)(wg * 64 + lane) * 32;
#pragma unroll
    for (int d = 0; d < 2; ++d)
#pragma unroll
      for (int i = 0; i < 4; ++i) {
        f32x4 v = ((const f32x4*)src)[d * 4 + i];
        oacc[d][i*4+0] += v[0]; oacc[d][i*4+1] += v[1];
        oacc[d][i*4+2] += v[2]; oacc[d][i*4+3] += v[3];
      }
  }

  // ---- epilogue: normalize, transpose via LDS, coalesced store ----
  u16* olw = (u16*)(smem + 1024) + (size_t)wg * 32 * 72;   // avoids lsarea
  float inv = 1.0f / lst;
#pragma unroll
  for (int d = 0; d < 2; ++d) {
#pragma unroll
    for (int i = 0; i < 8; ++i) {
      int r0 = 2 * i;
      int dh = d * 32 + (r0 & 3) + 8 * (r0 >> 2) + 4 * hi;
      uint32_t pk = cvtpk_bf16(oacc[d][r0] * inv, oacc[d][r0 + 1] * inv);
      *(uint32_t*)&olw[l32 * 72 + dh] = pk;
    }
  }
  __builtin_amdgcn_s_waitcnt(0);  // drain lgkm before same-wave readback
#pragma unroll
  for (int rr = 0; rr < 4; ++rr) {
    int row = rr * 8 + (lane >> 3);
    short8 v = *(const short8*)&olw[row * 72 + (lane & 7) * 8];
    int n = q0 + row;
    *(short8*)&AO[((size_t)b * NN + n) * DD + h * DHD + (lane & 7) * 8] = v;
  }
}

extern "C" void kernel_launch(void* const* d_in, const int* in_sizes, int n_in,
                              void* d_out, int out_size, void* d_ws, size_t ws_size,
                              hipStream_t stream) {
  const float* x  = (const float*)d_in[0];
  const float* Ww = (const float*)d_in[1];
  const float* Wb = (const float*)d_in[2];
  const float* ow = (const float*)d_in[3];
  const float* ob = (const float*)d_in[4];
  float* out = (float*)d_out;

  char* ws = (char*)d_ws;
  u16* xb  = (u16*)(ws);                       // 8 MB  x bf16 [4096][1024]
  u16* wwb = (u16*)(ws + ((size_t)8  << 20));  // 6 MB  W_w bf16 [3072][1024]
  u16* owb = (u16*)(ws + ((size_t)14 << 20));  // 2 MB  out_w bf16 [1024][1024]
  u16* Qb  = (u16*)(ws + ((size_t)16 << 20));  // 8 MB  Q [b,h,n,dh] (pre-scaled)
  u16* Kb  = (u16*)(ws + ((size_t)24 << 20));  // 8 MB  K [b,h,n,dh]
  u16* Vt  = (u16*)(ws + ((size_t)32 << 20));  // 8 MB  V^T [b,h,dh,n]
  u16* AO  = (u16*)(ws + ((size_t)40 << 20));  // 8 MB  attn out [b,n,h*dh]

  k_cvt_all<<<8192, 256, 0, stream>>>(x, Ww, ow, xb, wwb, owb);

  dim3 g1(QKVC / 128, MTOT / 128);  // (24, 32) -> 768 blocks, 3/CU
  k_gemm_bt<0, 128, 128><<<g1, 256, 0, stream>>>(xb, wwb, Wb, Qb, Kb, Vt, nullptr, MTOT, QKVC, DD);

  k_attn<<<512, 512, 0, stream>>>(Qb, Kb, Vt, AO);

  dim3 g3(DD / 64, MTOT / 64);      // (16, 64) -> 1024 blocks, 4/CU
  k_gemm64<<<g3, 256, 0, stream>>>(AO, owb, ob, out, MTOT, DD, DD);
}